// Round 8
// baseline (246.726 us; speedup 1.0000x reference)
//
#include <hip/hip_runtime.h>
#include <math.h>

// GraphSAGE 2-layer, mean aggregation, fp32.
// Round 8: single structural change vs R7 (passed, 235us). R7's top dispatch
// was deg_rank (72us): 1.6M device-scope atomics at ~2.2e10/s, each costing a
// 32B memory-side write-line (WRITE_SIZE evidence R1/R7). This round fuses
// the CSR scatter INTO the atomic pass using a fixed-capacity adjacency:
// pos = dst*CAP + rank is known at atomic time, so rank buffer, the 3 scan
// kernels, and scatter_kernel (ei re-read + 51MB scattered stores) are all
// deleted. CAP=48: deg ~ Poisson(16), P(any node >= 48) ~ 5e-6; stores are
// clamped so overflow cannot corrupt. Mean divides by TRUE deg.
// Experiment value: if the atomic pass is op-RATE-bound (hypothesis), the
// fused kernel stays ~80us and total drops ~45us; if write-BW-bound it rises
// to ~140us -> revert + bucketed atomic-free CSR next round.
// gather_mean / dense_v2 / final_kernel: R7 verbatim except adj indexing.

constexpr int N    = 100000;
constexpr int E    = 1600000;
constexpr int INC  = 19;
constexpr int HID  = 128;
constexpr int OUTC = 4;
constexpr int CAP  = 48;                // fixed adjacency capacity per node
constexpr int NB   = (N + 255) / 256;

// ---- kernel 0: detect whether edge_index arrived as int64 or int32 -------
__global__ void detect_idx64(const int* __restrict__ ei, int* __restrict__ flag) {
    __shared__ int any;
    if (threadIdx.x == 0) any = 0;
    __syncthreads();
    int v = 0;
    for (int k = threadIdx.x; k < 1024; k += blockDim.x)
        v |= ei[2 * k + 1];
    if (v) atomicOr(&any, 1);
    __syncthreads();
    if (threadIdx.x == 0) *flag = (any == 0) ? 1 : 0;
}

__device__ inline void load_edge(const int* __restrict__ ei, int e, int is64,
                                 int& src, int& dst) {
    if (is64) {
        src = ei[2 * e];
        dst = ei[2 * E + 2 * e];
    } else {
        src = ei[e];
        dst = ei[E + e];
    }
}

// ---- kernel 1: fused degree histogram + direct CSR scatter ----------------
__global__ void deg_scatter_kernel(const int* __restrict__ ei,
                                   int* __restrict__ deg,
                                   int* __restrict__ adj,
                                   const int* __restrict__ flag) {
    int e = blockIdx.x * blockDim.x + threadIdx.x;
    if (e >= E) return;
    int is64 = *flag;
    int src, dst;
    load_edge(ei, e, is64, src, dst);
    int r = atomicAdd(&deg[dst], 1);
    if (r < CAP) adj[dst * CAP + r] = src;
}

// ---- kernel 2: gather-mean, 32 lanes per node, one channel per lane ------
__global__ void gather_mean_kernel(const float* __restrict__ x,
                                   const int* __restrict__ adj,
                                   const int* __restrict__ deg,
                                   float* __restrict__ mean1) {
    int tid  = blockIdx.x * blockDim.x + threadIdx.x;
    int node = tid >> 5;
    int ln   = tid & 31;
    if (node >= N || ln >= INC) return;
    int d  = deg[node];
    int dm = (d < CAP) ? d : CAP;
    const int* ap = adj + (size_t)node * CAP;
    float a0 = 0.f, a1 = 0.f;
    int j = 0;
    for (; j + 1 < dm; j += 2) {
        int s0 = ap[j];
        int s1 = ap[j + 1];
        a0 += x[(size_t)s0 * INC + ln];
        a1 += x[(size_t)s1 * INC + ln];
    }
    if (j < dm) a0 += x[(size_t)ap[j] * INC + ln];
    float inv = 1.0f / fmaxf((float)d, 1.0f);
    mean1[(size_t)node * INC + ln] = (a0 + a1) * inv;
}

// ---- kernel 3: dense layer1 + layer2 projection, thread-per-node ----------
// (R7 verbatim) All weights in LDS, wave-uniform broadcast reads, no
// barriers after staging, accumulators statically indexed in registers.
__global__ __launch_bounds__(256) void dense_v2(
        const float* __restrict__ x,
        const float* __restrict__ mean1,
        const float* __restrict__ w1l,
        const float* __restrict__ w1r,
        const float* __restrict__ b1,
        const float* __restrict__ w2l,
        const float* __restrict__ w2r,
        float* __restrict__ g,
        float* __restrict__ s) {
    __shared__ float W1L[INC * HID];
    __shared__ float W1R[INC * HID];
    __shared__ float W2[HID * 8];
    __shared__ float B1[HID];

    int t = threadIdx.x;
    for (int k = t; k < INC * HID; k += 256) {
        W1L[k] = w1l[k];
        W1R[k] = w1r[k];
    }
    for (int k = t; k < HID * OUTC; k += 256) {
        int o = k >> 2, kk = k & 3;
        W2[o * 8 + kk]     = w2l[k];
        W2[o * 8 + 4 + kk] = w2r[k];
    }
    if (t < HID) B1[t] = b1[t];
    __syncthreads();

    int node = blockIdx.x * 256 + t;
    if (node >= N) return;

    float ms[INC], xs[INC];
#pragma unroll
    for (int c = 0; c < INC; ++c) {
        ms[c] = mean1[(size_t)node * INC + c];
        xs[c] = x[(size_t)node * INC + c];
    }

    float r[8] = {0.f, 0.f, 0.f, 0.f, 0.f, 0.f, 0.f, 0.f};
#pragma unroll 4
    for (int o = 0; o < HID; ++o) {
        float acc = B1[o];
#pragma unroll
        for (int c = 0; c < INC; ++c)
            acc += ms[c] * W1L[c * HID + o] + xs[c] * W1R[c * HID + o];
        float h = fmaxf(acc, 0.0f);
#pragma unroll
        for (int k = 0; k < 8; ++k)
            r[k] += h * W2[o * 8 + k];
    }

    *(float4*)(g + (size_t)node * OUTC) = make_float4(r[0], r[1], r[2], r[3]);
    *(float4*)(s + (size_t)node * OUTC) = make_float4(r[4], r[5], r[6], r[7]);
}

// ---- kernel 4: gather-mean(g) + self + bias + log_softmax -----------------
__global__ void final_kernel(const float* __restrict__ g,
                             const int* __restrict__ adj,
                             const int* __restrict__ deg,
                             const float* __restrict__ s,
                             const float* __restrict__ b2,
                             float* __restrict__ out) {
    int i = blockIdx.x * blockDim.x + threadIdx.x;
    if (i >= N) return;
    int d  = deg[i];
    int dm = (d < CAP) ? d : CAP;
    const int* ap = adj + (size_t)i * CAP;
    float4 acc = make_float4(0.f, 0.f, 0.f, 0.f);
    for (int j = 0; j < dm; ++j) {
        int sn = ap[j];
        float4 gv = *(const float4*)(g + (size_t)sn * OUTC);
        acc.x += gv.x; acc.y += gv.y; acc.z += gv.z; acc.w += gv.w;
    }
    float inv = 1.0f / fmaxf((float)d, 1.0f);
    float o[OUTC];
    o[0] = acc.x * inv + s[(size_t)i * OUTC + 0] + b2[0];
    o[1] = acc.y * inv + s[(size_t)i * OUTC + 1] + b2[1];
    o[2] = acc.z * inv + s[(size_t)i * OUTC + 2] + b2[2];
    o[3] = acc.w * inv + s[(size_t)i * OUTC + 3] + b2[3];
    float m = fmaxf(fmaxf(o[0], o[1]), fmaxf(o[2], o[3]));
    float sum = 0.f;
#pragma unroll
    for (int k = 0; k < OUTC; ++k)
        sum += expf(o[k] - m);
    float lse = logf(sum);
    float4 ov = make_float4(o[0] - m - lse, o[1] - m - lse,
                            o[2] - m - lse, o[3] - m - lse);
    *(float4*)(out + (size_t)i * OUTC) = ov;
}

extern "C" void kernel_launch(void* const* d_in, const int* in_sizes, int n_in,
                              void* d_out, int out_size, void* d_ws, size_t ws_size,
                              hipStream_t stream) {
    const float* x   = (const float*)d_in[0];
    const int*   ei  = (const int*)d_in[1];
    const float* w1l = (const float*)d_in[2];
    const float* w1r = (const float*)d_in[3];
    const float* b1  = (const float*)d_in[4];
    const float* w2l = (const float*)d_in[5];
    const float* w2r = (const float*)d_in[6];
    const float* b2  = (const float*)d_in[7];
    float* out = (float*)d_out;

    // workspace layout (4B units):
    // [flag 64][deg N][adj N*CAP][g 4N][s 4N][mean1 19N]  ~= 30.4 MB
    int*   ws    = (int*)d_ws;
    int*   flag  = ws;
    int*   deg   = ws + 64;
    int*   adj   = deg + N;
    float* g     = (float*)(adj + (size_t)N * CAP);
    float* s     = g + (size_t)N * OUTC;
    float* mean1 = s + (size_t)N * OUTC;

    hipMemsetAsync(deg, 0, (size_t)N * sizeof(int), stream);

    detect_idx64<<<1, 256, 0, stream>>>(ei, flag);
    deg_scatter_kernel<<<(E + 255) / 256, 256, 0, stream>>>(ei, deg, adj, flag);
    gather_mean_kernel<<<(N * 32 + 255) / 256, 256, 0, stream>>>(x, adj, deg, mean1);
    dense_v2<<<NB, 256, 0, stream>>>(x, mean1, w1l, w1r, b1, w2l, w2r, g, s);
    final_kernel<<<(N + 255) / 256, 256, 0, stream>>>(g, adj, deg, s, b2, out);
}

// Round 9
// 170.526 us; speedup vs baseline: 1.4469x; 1.4469x over previous
//
#include <hip/hip_runtime.h>
#include <math.h>

// GraphSAGE 2-layer, mean aggregation, fp32.
// Round 9: R7/R8 established the CSR build is bound by memory-side random
// line-ops (~2.3e10/s): 1.6M atomics + 1.6M random 4B stores cost ~32B-line
// each regardless of fusion. Fix: two-phase binned build.
//   Phase A (bin_kernel): per-block LDS count into 98 buckets (dst>>10),
//     ONE global atomic per (block,bucket) = 25K atomics total (64x fewer),
//     edges written as packed u32 (dstLocal<<17|src) in contiguous runs.
//   Phase B (bucket_csr): per-bucket counting sort entirely in LDS
//     (1024-entry hist + Hillis-Steele scan + cursors); adj writes confined
//     to the bucket's ~64KB L2-resident CSR segment -> write-merged.
//     Emits exact global deg/start.
// gather_mean / dense_v2 / final_kernel: R7-verbatim (passing) forms.
// No wave shuffles anywhere (R3/R5 bisect banned the family).

constexpr int N    = 100000;
constexpr int E    = 1600000;
constexpr int INC  = 19;
constexpr int HID  = 128;
constexpr int OUTC = 4;
constexpr int NB   = (N + 255) / 256;

constexpr int NBUK   = (N + 1023) >> 10;     // 98 buckets of 1024 nodes
constexpr int BCAP   = 24576;                // bucket capacity (mean 16384, >60 sigma)
constexpr int BA_BLK = 256;                  // phase-A blocks
constexpr int CHUNK  = (E + BA_BLK - 1) / BA_BLK;   // 6250 edges/block

// ---- kernel 0: detect whether edge_index arrived as int64 or int32 -------
__global__ void detect_idx64(const int* __restrict__ ei, int* __restrict__ flag) {
    __shared__ int any;
    if (threadIdx.x == 0) any = 0;
    __syncthreads();
    int v = 0;
    for (int k = threadIdx.x; k < 1024; k += blockDim.x)
        v |= ei[2 * k + 1];
    if (v) atomicOr(&any, 1);
    __syncthreads();
    if (threadIdx.x == 0) *flag = (any == 0) ? 1 : 0;
}

__device__ inline void load_edge(const int* __restrict__ ei, int e, int is64,
                                 int& src, int& dst) {
    if (is64) {
        src = ei[2 * e];
        dst = ei[2 * E + 2 * e];
    } else {
        src = ei[e];
        dst = ei[E + e];
    }
}

// ---- kernel 1 (phase A): bin edges into 98 bucket regions -----------------
__global__ __launch_bounds__(256) void bin_kernel(const int* __restrict__ ei,
                                                  const int* __restrict__ flag,
                                                  int* __restrict__ gcnt,
                                                  unsigned* __restrict__ be) {
    __shared__ int cnt[NBUK];
    __shared__ int base[NBUK];
    int t = threadIdx.x;
    for (int k = t; k < NBUK; k += 256) cnt[k] = 0;
    __syncthreads();

    int is64 = *flag;
    int lo = blockIdx.x * CHUNK;
    int hi = lo + CHUNK; if (hi > E) hi = E;

    // pass 1: count this chunk's bucket sizes (dst only)
    for (int e = lo + t; e < hi; e += 256) {
        int dst = is64 ? ei[2 * E + 2 * e] : ei[E + e];
        atomicAdd(&cnt[dst >> 10], 1);               // LDS atomic
    }
    __syncthreads();

    // reserve space: one global atomic per (block,bucket)
    for (int k = t; k < NBUK; k += 256) {
        base[k] = atomicAdd(&gcnt[k], cnt[k]);
        cnt[k] = 0;                                  // reuse as cursor
    }
    __syncthreads();

    // pass 2: write packed edges into bucket regions (contiguous runs)
    for (int e = lo + t; e < hi; e += 256) {
        int src, dst;
        load_edge(ei, e, is64, src, dst);
        int b = dst >> 10;
        int r = atomicAdd(&cnt[b], 1);               // LDS atomic
        int pos = base[b] + r;
        if (pos < BCAP)
            be[(size_t)b * BCAP + pos] = ((unsigned)(dst & 1023) << 17) | (unsigned)src;
    }
}

// ---- kernel 2: exclusive scan of bucket sizes (98 values, 1 block) --------
__global__ void scan_gcnt(const int* __restrict__ gcnt, int* __restrict__ gbase) {
    __shared__ int sd[128];
    int t = threadIdx.x;          // 128 threads
    int v = (t < NBUK) ? gcnt[t] : 0;
    sd[t] = v;
    __syncthreads();
    for (int off = 1; off < 128; off <<= 1) {
        int add = (t >= off) ? sd[t - off] : 0;
        __syncthreads();
        sd[t] += add;
        __syncthreads();
    }
    if (t < NBUK) gbase[t] = sd[t] - v;
}

// ---- kernel 3 (phase B): per-bucket counting sort -> adj/deg/start --------
__global__ __launch_bounds__(1024) void bucket_csr(const unsigned* __restrict__ be,
                                                   const int* __restrict__ gcnt,
                                                   const int* __restrict__ gbase,
                                                   int* __restrict__ adj,
                                                   int* __restrict__ deg,
                                                   int* __restrict__ start) {
    __shared__ int hist[1024];
    __shared__ int sloc[1024];
    __shared__ int cur[1024];
    int b = blockIdx.x;
    int t = threadIdx.x;

    hist[t] = 0;
    cur[t]  = 0;
    __syncthreads();

    int sz = gcnt[b]; if (sz > BCAP) sz = BCAP;
    const unsigned* bp = be + (size_t)b * BCAP;

    // pass 1: local degree histogram
    for (int i = t; i < sz; i += 1024) {
        int dl = bp[i] >> 17;
        atomicAdd(&hist[dl], 1);                     // LDS atomic
    }
    __syncthreads();

    // Hillis-Steele inclusive scan of hist into sloc (R7 scan pattern)
    int v = hist[t];
    sloc[t] = v;
    __syncthreads();
    for (int off = 1; off < 1024; off <<= 1) {
        int add = (t >= off) ? sloc[t - off] : 0;
        __syncthreads();
        sloc[t] += add;
        __syncthreads();
    }
    int sl = sloc[t] - v;                            // exclusive local start

    int gb = gbase[b];
    int node = b * 1024 + t;
    if (node < N) {
        deg[node]   = v;
        start[node] = gb + sl;
    }
    __syncthreads();

    // pass 2: scatter src into this bucket's CSR segment (L2-resident)
    for (int i = t; i < sz; i += 1024) {
        unsigned p = bp[i];
        int dl  = p >> 17;
        int src = (int)(p & 0x1FFFFu);
        int r = atomicAdd(&cur[dl], 1);              // LDS atomic
        adj[gb + (sloc[dl] - hist[dl]) + r] = src;
    }
}

// ---- kernel 4: gather-mean, 32 lanes per node, one channel per lane ------
// (R7 verbatim) No shuffles, no barriers: lane privately sums its channel.
__global__ void gather_mean_kernel(const float* __restrict__ x,
                                   const int* __restrict__ adj,
                                   const int* __restrict__ start,
                                   const int* __restrict__ deg,
                                   float* __restrict__ mean1) {
    int tid  = blockIdx.x * blockDim.x + threadIdx.x;
    int node = tid >> 5;
    int ln   = tid & 31;
    if (node >= N || ln >= INC) return;
    int d  = deg[node];
    int st = start[node];
    float a0 = 0.f, a1 = 0.f;
    int j = 0;
    for (; j + 1 < d; j += 2) {
        int s0 = adj[st + j];
        int s1 = adj[st + j + 1];
        a0 += x[(size_t)s0 * INC + ln];
        a1 += x[(size_t)s1 * INC + ln];
    }
    if (j < d) a0 += x[(size_t)adj[st + j] * INC + ln];
    float inv = 1.0f / fmaxf((float)d, 1.0f);
    mean1[(size_t)node * INC + ln] = (a0 + a1) * inv;
}

// ---- kernel 5: dense layer1 + layer2 projection, thread-per-node ----------
// (R7 verbatim) Weights in LDS, wave-uniform broadcast reads, no barriers
// after staging, accumulators statically indexed in registers.
__global__ __launch_bounds__(256) void dense_v2(
        const float* __restrict__ x,
        const float* __restrict__ mean1,
        const float* __restrict__ w1l,
        const float* __restrict__ w1r,
        const float* __restrict__ b1,
        const float* __restrict__ w2l,
        const float* __restrict__ w2r,
        float* __restrict__ g,
        float* __restrict__ s) {
    __shared__ float W1L[INC * HID];
    __shared__ float W1R[INC * HID];
    __shared__ float W2[HID * 8];
    __shared__ float B1[HID];

    int t = threadIdx.x;
    for (int k = t; k < INC * HID; k += 256) {
        W1L[k] = w1l[k];
        W1R[k] = w1r[k];
    }
    for (int k = t; k < HID * OUTC; k += 256) {
        int o = k >> 2, kk = k & 3;
        W2[o * 8 + kk]     = w2l[k];
        W2[o * 8 + 4 + kk] = w2r[k];
    }
    if (t < HID) B1[t] = b1[t];
    __syncthreads();

    int node = blockIdx.x * 256 + t;
    if (node >= N) return;

    float ms[INC], xs[INC];
#pragma unroll
    for (int c = 0; c < INC; ++c) {
        ms[c] = mean1[(size_t)node * INC + c];
        xs[c] = x[(size_t)node * INC + c];
    }

    float r[8] = {0.f, 0.f, 0.f, 0.f, 0.f, 0.f, 0.f, 0.f};
#pragma unroll 4
    for (int o = 0; o < HID; ++o) {
        float acc = B1[o];
#pragma unroll
        for (int c = 0; c < INC; ++c)
            acc += ms[c] * W1L[c * HID + o] + xs[c] * W1R[c * HID + o];
        float h = fmaxf(acc, 0.0f);
#pragma unroll
        for (int k = 0; k < 8; ++k)
            r[k] += h * W2[o * 8 + k];
    }

    *(float4*)(g + (size_t)node * OUTC) = make_float4(r[0], r[1], r[2], r[3]);
    *(float4*)(s + (size_t)node * OUTC) = make_float4(r[4], r[5], r[6], r[7]);
}

// ---- kernel 6: gather-mean(g) + self + bias + log_softmax (R7 verbatim) ---
__global__ void final_kernel(const float* __restrict__ g,
                             const int* __restrict__ adj,
                             const int* __restrict__ start,
                             const int* __restrict__ deg,
                             const float* __restrict__ s,
                             const float* __restrict__ b2,
                             float* __restrict__ out) {
    int i = blockIdx.x * blockDim.x + threadIdx.x;
    if (i >= N) return;
    int d  = deg[i];
    int st = start[i];
    float4 acc = make_float4(0.f, 0.f, 0.f, 0.f);
    for (int j = 0; j < d; ++j) {
        int sn = adj[st + j];
        float4 gv = *(const float4*)(g + (size_t)sn * OUTC);
        acc.x += gv.x; acc.y += gv.y; acc.z += gv.z; acc.w += gv.w;
    }
    float inv = 1.0f / fmaxf((float)d, 1.0f);
    float o[OUTC];
    o[0] = acc.x * inv + s[(size_t)i * OUTC + 0] + b2[0];
    o[1] = acc.y * inv + s[(size_t)i * OUTC + 1] + b2[1];
    o[2] = acc.z * inv + s[(size_t)i * OUTC + 2] + b2[2];
    o[3] = acc.w * inv + s[(size_t)i * OUTC + 3] + b2[3];
    float m = fmaxf(fmaxf(o[0], o[1]), fmaxf(o[2], o[3]));
    float sum = 0.f;
#pragma unroll
    for (int k = 0; k < OUTC; ++k)
        sum += expf(o[k] - m);
    float lse = logf(sum);
    float4 ov = make_float4(o[0] - m - lse, o[1] - m - lse,
                            o[2] - m - lse, o[3] - m - lse);
    *(float4*)(out + (size_t)i * OUTC) = ov;
}

extern "C" void kernel_launch(void* const* d_in, const int* in_sizes, int n_in,
                              void* d_out, int out_size, void* d_ws, size_t ws_size,
                              hipStream_t stream) {
    const float* x   = (const float*)d_in[0];
    const int*   ei  = (const int*)d_in[1];
    const float* w1l = (const float*)d_in[2];
    const float* w1r = (const float*)d_in[3];
    const float* b1  = (const float*)d_in[4];
    const float* w2l = (const float*)d_in[5];
    const float* w2r = (const float*)d_in[6];
    const float* b2  = (const float*)d_in[7];
    float* out = (float*)d_out;

    // workspace layout (4B units), ~27.6 MB:
    // [flag 64][gcnt 128][gbase 128][deg N][start N][be NBUK*BCAP][adj E]
    // [g 4N][s 4N][mean1 19N]
    int*      ws    = (int*)d_ws;
    int*      flag  = ws;
    int*      gcnt  = ws + 64;
    int*      gbase = gcnt + 128;
    int*      deg   = gbase + 128;
    int*      start = deg + N;
    unsigned* be    = (unsigned*)(start + N);
    int*      adj   = (int*)(be + (size_t)NBUK * BCAP);
    float*    g     = (float*)(adj + E);
    float*    s     = g + (size_t)N * OUTC;
    float*    mean1 = s + (size_t)N * OUTC;

    hipMemsetAsync(gcnt, 0, 128 * sizeof(int), stream);

    detect_idx64<<<1, 256, 0, stream>>>(ei, flag);
    bin_kernel<<<BA_BLK, 256, 0, stream>>>(ei, flag, gcnt, be);
    scan_gcnt<<<1, 128, 0, stream>>>(gcnt, gbase);
    bucket_csr<<<NBUK, 1024, 0, stream>>>(be, gcnt, gbase, adj, deg, start);
    gather_mean_kernel<<<(N * 32 + 255) / 256, 256, 0, stream>>>(x, adj, start, deg, mean1);
    dense_v2<<<NB, 256, 0, stream>>>(x, mean1, w1l, w1r, b1, w2l, w2r, g, s);
    final_kernel<<<(N + 255) / 256, 256, 0, stream>>>(g, adj, start, deg, s, b2, out);
}

// Round 10
// 149.375 us; speedup vs baseline: 1.6517x; 1.1416x over previous
//
#include <hip/hip_runtime.h>
#include <math.h>

// GraphSAGE 2-layer, mean aggregation, fp32.
// Round 10: two low-risk changes vs R9 (passed, 170us, top = gather_mean
// 52us, latency-bound: 19/32 lanes active, 2 outstanding row-loads).
//  1) gather_mean: dense (node,channel) thread packing (node=tid/19) ->
//     100% lane utilization; 4-way neighbor unroll -> 4 x-row loads in
//     flight; mean1 writes fully coalesced.
//  2) final_kernel: 4-way unroll of the g-gather loop (reassociation only).
// CSR build (binned, R9) / dense_v2 / everything else: verbatim.

constexpr int N    = 100000;
constexpr int E    = 1600000;
constexpr int INC  = 19;
constexpr int HID  = 128;
constexpr int OUTC = 4;
constexpr int NB   = (N + 255) / 256;

constexpr int NBUK   = (N + 1023) >> 10;     // 98 buckets of 1024 nodes
constexpr int BCAP   = 24576;                // bucket capacity (mean 16384)
constexpr int BA_BLK = 256;                  // phase-A blocks
constexpr int CHUNK  = (E + BA_BLK - 1) / BA_BLK;   // 6250 edges/block

// ---- kernel 0: detect whether edge_index arrived as int64 or int32 -------
__global__ void detect_idx64(const int* __restrict__ ei, int* __restrict__ flag) {
    __shared__ int any;
    if (threadIdx.x == 0) any = 0;
    __syncthreads();
    int v = 0;
    for (int k = threadIdx.x; k < 1024; k += blockDim.x)
        v |= ei[2 * k + 1];
    if (v) atomicOr(&any, 1);
    __syncthreads();
    if (threadIdx.x == 0) *flag = (any == 0) ? 1 : 0;
}

__device__ inline void load_edge(const int* __restrict__ ei, int e, int is64,
                                 int& src, int& dst) {
    if (is64) {
        src = ei[2 * e];
        dst = ei[2 * E + 2 * e];
    } else {
        src = ei[e];
        dst = ei[E + e];
    }
}

// ---- kernel 1 (phase A): bin edges into 98 bucket regions (R9 verbatim) ---
__global__ __launch_bounds__(256) void bin_kernel(const int* __restrict__ ei,
                                                  const int* __restrict__ flag,
                                                  int* __restrict__ gcnt,
                                                  unsigned* __restrict__ be) {
    __shared__ int cnt[NBUK];
    __shared__ int base[NBUK];
    int t = threadIdx.x;
    for (int k = t; k < NBUK; k += 256) cnt[k] = 0;
    __syncthreads();

    int is64 = *flag;
    int lo = blockIdx.x * CHUNK;
    int hi = lo + CHUNK; if (hi > E) hi = E;

    for (int e = lo + t; e < hi; e += 256) {
        int dst = is64 ? ei[2 * E + 2 * e] : ei[E + e];
        atomicAdd(&cnt[dst >> 10], 1);               // LDS atomic
    }
    __syncthreads();

    for (int k = t; k < NBUK; k += 256) {
        base[k] = atomicAdd(&gcnt[k], cnt[k]);
        cnt[k] = 0;                                  // reuse as cursor
    }
    __syncthreads();

    for (int e = lo + t; e < hi; e += 256) {
        int src, dst;
        load_edge(ei, e, is64, src, dst);
        int b = dst >> 10;
        int r = atomicAdd(&cnt[b], 1);               // LDS atomic
        int pos = base[b] + r;
        if (pos < BCAP)
            be[(size_t)b * BCAP + pos] = ((unsigned)(dst & 1023) << 17) | (unsigned)src;
    }
}

// ---- kernel 2: exclusive scan of bucket sizes (R9 verbatim) ---------------
__global__ void scan_gcnt(const int* __restrict__ gcnt, int* __restrict__ gbase) {
    __shared__ int sd[128];
    int t = threadIdx.x;          // 128 threads
    int v = (t < NBUK) ? gcnt[t] : 0;
    sd[t] = v;
    __syncthreads();
    for (int off = 1; off < 128; off <<= 1) {
        int add = (t >= off) ? sd[t - off] : 0;
        __syncthreads();
        sd[t] += add;
        __syncthreads();
    }
    if (t < NBUK) gbase[t] = sd[t] - v;
}

// ---- kernel 3 (phase B): per-bucket counting sort (R9 verbatim) -----------
__global__ __launch_bounds__(1024) void bucket_csr(const unsigned* __restrict__ be,
                                                   const int* __restrict__ gcnt,
                                                   const int* __restrict__ gbase,
                                                   int* __restrict__ adj,
                                                   int* __restrict__ deg,
                                                   int* __restrict__ start) {
    __shared__ int hist[1024];
    __shared__ int sloc[1024];
    __shared__ int cur[1024];
    int b = blockIdx.x;
    int t = threadIdx.x;

    hist[t] = 0;
    cur[t]  = 0;
    __syncthreads();

    int sz = gcnt[b]; if (sz > BCAP) sz = BCAP;
    const unsigned* bp = be + (size_t)b * BCAP;

    for (int i = t; i < sz; i += 1024) {
        int dl = bp[i] >> 17;
        atomicAdd(&hist[dl], 1);                     // LDS atomic
    }
    __syncthreads();

    int v = hist[t];
    sloc[t] = v;
    __syncthreads();
    for (int off = 1; off < 1024; off <<= 1) {
        int add = (t >= off) ? sloc[t - off] : 0;
        __syncthreads();
        sloc[t] += add;
        __syncthreads();
    }
    int sl = sloc[t] - v;                            // exclusive local start

    int gb = gbase[b];
    int node = b * 1024 + t;
    if (node < N) {
        deg[node]   = v;
        start[node] = gb + sl;
    }
    __syncthreads();

    for (int i = t; i < sz; i += 1024) {
        unsigned p = bp[i];
        int dl  = p >> 17;
        int src = (int)(p & 0x1FFFFu);
        int r = atomicAdd(&cur[dl], 1);              // LDS atomic
        adj[gb + (sloc[dl] - hist[dl]) + r] = src;
    }
}

// ---- kernel 4: gather-mean, dense (node,channel) packing, 4-way unroll ----
__global__ void gather_mean_v2(const float* __restrict__ x,
                               const int* __restrict__ adj,
                               const int* __restrict__ start,
                               const int* __restrict__ deg,
                               float* __restrict__ mean1) {
    int tid = blockIdx.x * blockDim.x + threadIdx.x;
    if (tid >= N * INC) return;
    int node = tid / INC;                 // magic-mul division
    int ln   = tid - node * INC;
    int d  = deg[node];
    int st = start[node];
    float a0 = 0.f, a1 = 0.f, a2 = 0.f, a3 = 0.f;
    int j = 0;
    for (; j + 3 < d; j += 4) {
        int s0 = adj[st + j];
        int s1 = adj[st + j + 1];
        int s2 = adj[st + j + 2];
        int s3 = adj[st + j + 3];
        a0 += x[(size_t)s0 * INC + ln];
        a1 += x[(size_t)s1 * INC + ln];
        a2 += x[(size_t)s2 * INC + ln];
        a3 += x[(size_t)s3 * INC + ln];
    }
    for (; j < d; ++j)
        a0 += x[(size_t)adj[st + j] * INC + ln];
    float inv = 1.0f / fmaxf((float)d, 1.0f);
    mean1[tid] = ((a0 + a1) + (a2 + a3)) * inv;   // mean1[node*INC+ln], coalesced
}

// ---- kernel 5: dense layer1 + layer2 projection, thread-per-node ----------
// (R7/R9 verbatim) Weights in LDS, wave-uniform broadcast reads.
__global__ __launch_bounds__(256) void dense_v2(
        const float* __restrict__ x,
        const float* __restrict__ mean1,
        const float* __restrict__ w1l,
        const float* __restrict__ w1r,
        const float* __restrict__ b1,
        const float* __restrict__ w2l,
        const float* __restrict__ w2r,
        float* __restrict__ g,
        float* __restrict__ s) {
    __shared__ float W1L[INC * HID];
    __shared__ float W1R[INC * HID];
    __shared__ float W2[HID * 8];
    __shared__ float B1[HID];

    int t = threadIdx.x;
    for (int k = t; k < INC * HID; k += 256) {
        W1L[k] = w1l[k];
        W1R[k] = w1r[k];
    }
    for (int k = t; k < HID * OUTC; k += 256) {
        int o = k >> 2, kk = k & 3;
        W2[o * 8 + kk]     = w2l[k];
        W2[o * 8 + 4 + kk] = w2r[k];
    }
    if (t < HID) B1[t] = b1[t];
    __syncthreads();

    int node = blockIdx.x * 256 + t;
    if (node >= N) return;

    float ms[INC], xs[INC];
#pragma unroll
    for (int c = 0; c < INC; ++c) {
        ms[c] = mean1[(size_t)node * INC + c];
        xs[c] = x[(size_t)node * INC + c];
    }

    float r[8] = {0.f, 0.f, 0.f, 0.f, 0.f, 0.f, 0.f, 0.f};
#pragma unroll 4
    for (int o = 0; o < HID; ++o) {
        float acc = B1[o];
#pragma unroll
        for (int c = 0; c < INC; ++c)
            acc += ms[c] * W1L[c * HID + o] + xs[c] * W1R[c * HID + o];
        float h = fmaxf(acc, 0.0f);
#pragma unroll
        for (int k = 0; k < 8; ++k)
            r[k] += h * W2[o * 8 + k];
    }

    *(float4*)(g + (size_t)node * OUTC) = make_float4(r[0], r[1], r[2], r[3]);
    *(float4*)(s + (size_t)node * OUTC) = make_float4(r[4], r[5], r[6], r[7]);
}

// ---- kernel 6: gather-mean(g) + self + bias + log_softmax, 4-way unroll ---
__global__ void final_kernel(const float* __restrict__ g,
                             const int* __restrict__ adj,
                             const int* __restrict__ start,
                             const int* __restrict__ deg,
                             const float* __restrict__ s,
                             const float* __restrict__ b2,
                             float* __restrict__ out) {
    int i = blockIdx.x * blockDim.x + threadIdx.x;
    if (i >= N) return;
    int d  = deg[i];
    int st = start[i];
    float4 A = make_float4(0.f, 0.f, 0.f, 0.f);
    float4 B = make_float4(0.f, 0.f, 0.f, 0.f);
    float4 C = make_float4(0.f, 0.f, 0.f, 0.f);
    float4 D = make_float4(0.f, 0.f, 0.f, 0.f);
    int j = 0;
    for (; j + 3 < d; j += 4) {
        int s0 = adj[st + j];
        int s1 = adj[st + j + 1];
        int s2 = adj[st + j + 2];
        int s3 = adj[st + j + 3];
        float4 g0 = *(const float4*)(g + (size_t)s0 * OUTC);
        float4 g1 = *(const float4*)(g + (size_t)s1 * OUTC);
        float4 g2 = *(const float4*)(g + (size_t)s2 * OUTC);
        float4 g3 = *(const float4*)(g + (size_t)s3 * OUTC);
        A.x += g0.x; A.y += g0.y; A.z += g0.z; A.w += g0.w;
        B.x += g1.x; B.y += g1.y; B.z += g1.z; B.w += g1.w;
        C.x += g2.x; C.y += g2.y; C.z += g2.z; C.w += g2.w;
        D.x += g3.x; D.y += g3.y; D.z += g3.z; D.w += g3.w;
    }
    for (; j < d; ++j) {
        int sn = adj[st + j];
        float4 gv = *(const float4*)(g + (size_t)sn * OUTC);
        A.x += gv.x; A.y += gv.y; A.z += gv.z; A.w += gv.w;
    }
    float4 acc = make_float4((A.x + B.x) + (C.x + D.x),
                             (A.y + B.y) + (C.y + D.y),
                             (A.z + B.z) + (C.z + D.z),
                             (A.w + B.w) + (C.w + D.w));
    float inv = 1.0f / fmaxf((float)d, 1.0f);
    float o[OUTC];
    o[0] = acc.x * inv + s[(size_t)i * OUTC + 0] + b2[0];
    o[1] = acc.y * inv + s[(size_t)i * OUTC + 1] + b2[1];
    o[2] = acc.z * inv + s[(size_t)i * OUTC + 2] + b2[2];
    o[3] = acc.w * inv + s[(size_t)i * OUTC + 3] + b2[3];
    float m = fmaxf(fmaxf(o[0], o[1]), fmaxf(o[2], o[3]));
    float sum = 0.f;
#pragma unroll
    for (int k = 0; k < OUTC; ++k)
        sum += expf(o[k] - m);
    float lse = logf(sum);
    float4 ov = make_float4(o[0] - m - lse, o[1] - m - lse,
                            o[2] - m - lse, o[3] - m - lse);
    *(float4*)(out + (size_t)i * OUTC) = ov;
}

extern "C" void kernel_launch(void* const* d_in, const int* in_sizes, int n_in,
                              void* d_out, int out_size, void* d_ws, size_t ws_size,
                              hipStream_t stream) {
    const float* x   = (const float*)d_in[0];
    const int*   ei  = (const int*)d_in[1];
    const float* w1l = (const float*)d_in[2];
    const float* w1r = (const float*)d_in[3];
    const float* b1  = (const float*)d_in[4];
    const float* w2l = (const float*)d_in[5];
    const float* w2r = (const float*)d_in[6];
    const float* b2  = (const float*)d_in[7];
    float* out = (float*)d_out;

    // workspace layout (4B units), ~27.6 MB:
    // [flag 64][gcnt 128][gbase 128][deg N][start N][be NBUK*BCAP][adj E]
    // [g 4N][s 4N][mean1 19N]
    int*      ws    = (int*)d_ws;
    int*      flag  = ws;
    int*      gcnt  = ws + 64;
    int*      gbase = gcnt + 128;
    int*      deg   = gbase + 128;
    int*      start = deg + N;
    unsigned* be    = (unsigned*)(start + N);
    int*      adj   = (int*)(be + (size_t)NBUK * BCAP);
    float*    g     = (float*)(adj + E);
    float*    s     = g + (size_t)N * OUTC;
    float*    mean1 = s + (size_t)N * OUTC;

    hipMemsetAsync(gcnt, 0, 128 * sizeof(int), stream);

    detect_idx64<<<1, 256, 0, stream>>>(ei, flag);
    bin_kernel<<<BA_BLK, 256, 0, stream>>>(ei, flag, gcnt, be);
    scan_gcnt<<<1, 128, 0, stream>>>(gcnt, gbase);
    bucket_csr<<<NBUK, 1024, 0, stream>>>(be, gcnt, gbase, adj, deg, start);
    gather_mean_v2<<<(N * INC + 255) / 256, 256, 0, stream>>>(x, adj, start, deg, mean1);
    dense_v2<<<NB, 256, 0, stream>>>(x, mean1, w1l, w1r, b1, w2l, w2r, g, s);
    final_kernel<<<(N + 255) / 256, 256, 0, stream>>>(g, adj, start, deg, s, b2, out);
}